// Round 1
// baseline (301.722 us; speedup 1.0000x reference)
//
#include <hip/hip_runtime.h>

// TGCNCell: h_agg = segment_sum(x[src], dst); gates = h_agg @ W_ih.T + b_ih + b_hh
// c = sigmoid(i)*tanh(g); h = sigmoid(o)*tanh(c); out = relu(h)
// f-gate and W_hh are unused by the reference forward pass.

constexpr int NN = 100000;   // nodes
constexpr int NE = 1600000;  // edges
constexpr int F  = 32;       // feats (in == out)

// ---------------------------------------------------------------------------
// Kernel 1: edge scatter-add.  thread id -> (edge, feat).
// Lanes 0..31 of each half-wave share one edge: x-row read is one coalesced
// 128B segment; atomicAdd targets 32 consecutive floats (hardware f32 atomic,
// executes at L2 -- h_agg is 12.8MB, L2-resident).
// ---------------------------------------------------------------------------
__global__ __launch_bounds__(256) void edge_scatter(
    const float* __restrict__ x,
    const int*   __restrict__ src,
    const int*   __restrict__ dst,
    float*       __restrict__ hagg)
{
    int id = blockIdx.x * 256 + threadIdx.x;
    int e  = id >> 5;
    int f  = id & 31;
    if (e >= NE) return;
    int s = src[e];
    int d = dst[e];
    float v = x[(s << 5) + f];
    unsafeAtomicAdd(hagg + (d << 5) + f, v);   // global_atomic_add_f32
}

// ---------------------------------------------------------------------------
// Kernel 2: fused gates GEMM + activations.
// W_ih (128x32 row-major) staged in LDS (16KB); each thread computes 2 nodes
// so every ds_read_b128 of W feeds 2 FMAs per element -> FMA-bound not
// LDS-bound.  Only i (rows 0:32), g (64:96), o (96:128) gates are computed.
// ---------------------------------------------------------------------------
__device__ __forceinline__ float sigm(float v)  { return 1.0f / (1.0f + __expf(-v)); }
__device__ __forceinline__ float tanhf_(float v){ return 1.0f - 2.0f / (__expf(2.0f * v) + 1.0f); }

__global__ __launch_bounds__(256) void gates_act(
    const float* __restrict__ hagg,
    const float* __restrict__ W,      // (128,32) row-major
    const float* __restrict__ b_ih,
    const float* __restrict__ b_hh,
    float*       __restrict__ out)
{
    __shared__ float Ws[128 * 32];
    __shared__ float bs[128];
    const int t = threadIdx.x;

    #pragma unroll
    for (int i = 0; i < 16; ++i) Ws[t + 256 * i] = W[t + 256 * i];
    if (t < 128) bs[t] = b_ih[t] + b_hh[t];
    __syncthreads();

    const int n0 = blockIdx.x * 512 + t;
    const int n1 = n0 + 256;
    const bool v0 = (n0 < NN), v1 = (n1 < NN);
    if (!v0) return;  // n1 > n0, so nothing to do

    float h0[32], h1[32];
    {
        const float4* p0 = reinterpret_cast<const float4*>(hagg + (size_t)n0 * F);
        const float4* p1 = reinterpret_cast<const float4*>(hagg + (size_t)n1 * F);
        #pragma unroll
        for (int k = 0; k < 8; ++k) {
            float4 a = p0[k];
            h0[4*k+0] = a.x; h0[4*k+1] = a.y; h0[4*k+2] = a.z; h0[4*k+3] = a.w;
            float4 b = v1 ? p1[k] : float4{0.f, 0.f, 0.f, 0.f};
            h1[4*k+0] = b.x; h1[4*k+1] = b.y; h1[4*k+2] = b.z; h1[4*k+3] = b.w;
        }
    }

    const float4* wv = reinterpret_cast<const float4*>(Ws);

    #pragma unroll 4
    for (int j = 0; j < 32; ++j) {
        float ai0 = bs[j], ag0 = bs[64 + j], ao0 = bs[96 + j];
        float ai1 = ai0,   ag1 = ag0,        ao1 = ao0;
        #pragma unroll
        for (int kq = 0; kq < 8; ++kq) {
            const float4 wi = wv[(j      ) * 8 + kq];
            const float4 wg = wv[(64 + j) * 8 + kq];
            const float4 wo = wv[(96 + j) * 8 + kq];
            const int k = 4 * kq;
            ai0 += h0[k]*wi.x + h0[k+1]*wi.y + h0[k+2]*wi.z + h0[k+3]*wi.w;
            ag0 += h0[k]*wg.x + h0[k+1]*wg.y + h0[k+2]*wg.z + h0[k+3]*wg.w;
            ao0 += h0[k]*wo.x + h0[k+1]*wo.y + h0[k+2]*wo.z + h0[k+3]*wo.w;
            ai1 += h1[k]*wi.x + h1[k+1]*wi.y + h1[k+2]*wi.z + h1[k+3]*wi.w;
            ag1 += h1[k]*wg.x + h1[k+1]*wg.y + h1[k+2]*wg.z + h1[k+3]*wg.w;
            ao1 += h1[k]*wo.x + h1[k+1]*wo.y + h1[k+2]*wo.z + h1[k+3]*wo.w;
        }
        {
            float c  = sigm(ai0) * tanhf_(ag0);
            float hv = sigm(ao0) * tanhf_(c);
            out[(size_t)n0 * F + j] = fmaxf(hv, 0.f);
        }
        if (v1) {
            float c  = sigm(ai1) * tanhf_(ag1);
            float hv = sigm(ao1) * tanhf_(c);
            out[(size_t)n1 * F + j] = fmaxf(hv, 0.f);
        }
    }
}

// ---------------------------------------------------------------------------
extern "C" void kernel_launch(void* const* d_in, const int* in_sizes, int n_in,
                              void* d_out, int out_size, void* d_ws, size_t ws_size,
                              hipStream_t stream) {
    const float* x    = (const float*)d_in[0];
    const int*   src  = (const int*)  d_in[1];
    const int*   dst  = (const int*)  d_in[2];
    const float* W_ih = (const float*)d_in[3];
    // d_in[4] = W_hh : numerically unused by the reference forward pass
    const float* b_ih = (const float*)d_in[5];
    const float* b_hh = (const float*)d_in[6];
    float* out  = (float*)d_out;
    float* hagg = (float*)d_ws;                       // NN*F floats = 12.8 MB

    hipMemsetAsync(hagg, 0, (size_t)NN * F * sizeof(float), stream);

    {   // scatter: NE*32 threads
        const int total  = NE * F;                    // 51.2M
        const int blocks = total / 256;               // exactly 200000
        edge_scatter<<<blocks, 256, 0, stream>>>(x, src, dst, hagg);
    }
    {   // gates: 2 nodes per thread
        const int blocks = (NN + 511) / 512;          // 196
        gates_act<<<blocks, 256, 0, stream>>>(hagg, W_ih, b_ih, b_hh, out);
    }
}